// Round 4
// baseline (1473.469 us; speedup 1.0000x reference)
//
#include <hip/hip_runtime.h>

#define N_NODES 50000
#define N_EDGES 600000
#define HC 256
#define NH 8

typedef short s8v __attribute__((ext_vector_type(8)));
typedef float f4v __attribute__((ext_vector_type(4)));
typedef _Float16 h4v __attribute__((ext_vector_type(4)));
typedef __attribute__((address_space(1))) const unsigned int as1_cu32;
typedef __attribute__((address_space(3))) unsigned int as3_u32;

__device__ inline ushort f2bf(float f) {
  unsigned u = __float_as_uint(f);
  unsigned r = u + 0x7FFF + ((u >> 16) & 1);  // RNE
  return (ushort)(r >> 16);
}

// ---------------------------------------------------------------- CSR build
__global__ void k_init_cnt(int* __restrict__ cnt) {
  int i = blockIdx.x * 256 + threadIdx.x;
  if (i < N_NODES) cnt[i] = 1;  // self-loop
}

__global__ void k_count(const int* __restrict__ dstE, int* __restrict__ cnt) {
  int e = blockIdx.x * 256 + threadIdx.x;
  if (e < N_EDGES) atomicAdd(&cnt[dstE[e]], 1);
}

__global__ void k_scan_bsum(const int* __restrict__ cnt, int* __restrict__ bsum) {
  __shared__ int sd[256];
  int i = blockIdx.x * 256 + threadIdx.x;
  sd[threadIdx.x] = (i < N_NODES) ? cnt[i] : 0;
  __syncthreads();
  for (int o = 128; o > 0; o >>= 1) {
    if (threadIdx.x < o) sd[threadIdx.x] += sd[threadIdx.x + o];
    __syncthreads();
  }
  if (threadIdx.x == 0) bsum[blockIdx.x] = sd[0];
}

__global__ void k_scan_offsets(int* __restrict__ bsum, int nb) {
  __shared__ int s[256];
  int t = threadIdx.x;
  int v = (t < nb) ? bsum[t] : 0;
  s[t] = v; __syncthreads();
  for (int o = 1; o < 256; o <<= 1) {
    int x = (t >= o) ? s[t - o] : 0;
    __syncthreads();
    s[t] += x;
    __syncthreads();
  }
  if (t < nb) bsum[t] = s[t] - v;  // exclusive
}

__global__ void k_scan_write(const int* __restrict__ cnt, const int* __restrict__ bsum,
                             int* __restrict__ rowptr, int* __restrict__ fillptr) {
  __shared__ int s[256];
  int t = threadIdx.x;
  int i = blockIdx.x * 256 + t;
  int v = (i < N_NODES) ? cnt[i] : 0;
  s[t] = v; __syncthreads();
  for (int o = 1; o < 256; o <<= 1) {
    int x = (t >= o) ? s[t - o] : 0;
    __syncthreads();
    s[t] += x;
    __syncthreads();
  }
  int excl = s[t] - v + bsum[blockIdx.x];
  if (i < N_NODES) {
    rowptr[i] = excl;
    fillptr[i] = excl;
    if (i == N_NODES - 1) rowptr[N_NODES] = excl + v;
  }
}

__global__ void k_fill(const int* __restrict__ srcE, const int* __restrict__ dstE,
                       int* __restrict__ fillptr, int* __restrict__ srcs) {
  int i = blockIdx.x * 256 + threadIdx.x;
  if (i < N_NODES) {
    int pos = atomicAdd(&fillptr[i], 1);
    srcs[pos] = i;                       // self-loop
  } else if (i < N_NODES + N_EDGES) {
    int e = i - N_NODES;
    int pos = atomicAdd(&fillptr[dstE[e]], 1);
    srcs[pos] = srcE[e];
  }
}

// ---------------------------------------------------------------- fp32 -> bf16 converts
__global__ void k_cvt_x(const float* __restrict__ X, ushort* __restrict__ Xb) {
  size_t i = ((size_t)blockIdx.x * 256 + threadIdx.x) * 4;
  float4 x4 = *(const float4*)&X[i];
  ushort4 o;
  o.x = f2bf(x4.x); o.y = f2bf(x4.y); o.z = f2bf(x4.z); o.w = f2bf(x4.w);
  *(ushort4*)&Xb[i] = o;
}

// W[K][Nw] fp32 -> Wt[Nw][K] bf16 (transpose + convert)
__global__ void k_cvt_wt(const float* __restrict__ W, ushort* __restrict__ Wt, int K, int Nw) {
  __shared__ ushort s[32][33];
  int tx = threadIdx.x & 31, ty = threadIdx.x >> 5;
  int k0 = blockIdx.x * 32, n0 = blockIdx.y * 32;
  for (int j = 0; j < 32; j += 8)
    s[ty + j][tx] = f2bf(W[(size_t)(k0 + ty + j) * Nw + n0 + tx]);
  __syncthreads();
  for (int j = 0; j < 32; j += 8)
    Wt[(size_t)(n0 + ty + j) * K + k0 + tx] = s[tx][ty + j];
}

// pack [muW | lvW | auxW | 0] -> Wth[128][256] bf16
__global__ void k_pack_head(const float* __restrict__ muW, const float* __restrict__ lvW,
                            const float* __restrict__ auxW, ushort* __restrict__ Wth) {
  int n = blockIdx.x;   // 0..127
  int k = threadIdx.x;  // 0..255
  float v = 0.f;
  if (n < 32) v = muW[k * 32 + n];
  else if (n < 64) v = lvW[k * 32 + (n - 32)];
  else if (n < 94) v = auxW[k * 30 + (n - 64)];
  Wth[n * 256 + k] = f2bf(v);
}

// ---------------------------------------------------------------- bf16 MFMA GEMM (m97-style)
// A: bf16 [M][K] row-major. Wt: bf16 [N][K]. Block tile 128x128, K-tile 64.
// LDS staged via global_load_lds width=16 directly in fragment order.
// OutT: float or _Float16.
template <typename OutT>
__launch_bounds__(256)
__global__ void k_gemm_bf16(const ushort* __restrict__ A, const ushort* __restrict__ Wt,
                            const float* __restrict__ bias, OutT* __restrict__ Out,
                            int M, int K, int ldc) {
  __shared__ __align__(16) ushort As[16 * 512];  // 16 KB
  __shared__ __align__(16) ushort Bs[16 * 512];  // 16 KB
  int t = threadIdx.x, w = t >> 6, L = t & 63;
  int bm = blockIdx.x * 128, bn = blockIdx.y * 128;
  int lrow = L & 15, lcol = (L >> 4) * 8;

  const ushort* ga[4];
  const ushort* gb[4];
#pragma unroll
  for (int u = 0; u < 4; u++) {
    int i = w * 4 + u;
    int mt = i >> 1, ks = i & 1;
    int arow = bm + mt * 16 + lrow;
    if (arow >= M) arow = M - 1;
    ga[u] = A + (size_t)arow * K + ks * 32 + lcol;
    int brow = bn + mt * 16 + lrow;
    gb[u] = Wt + (size_t)brow * K + ks * 32 + lcol;
  }

  f4v acc[4][4];
  f4v zero = {0.f, 0.f, 0.f, 0.f};
#pragma unroll
  for (int mi = 0; mi < 4; mi++)
#pragma unroll
    for (int ni = 0; ni < 4; ni++) acc[mi][ni] = zero;

  int wm = (w >> 1) * 4;
  int wn = (w & 1) * 4;

  int nk = K >> 6;
  for (int kt = 0; kt < nk; kt++) {
#pragma unroll
    for (int u = 0; u < 4; u++) {
      int i = w * 4 + u;
      __builtin_amdgcn_global_load_lds((as1_cu32*)ga[u], (as3_u32*)&As[i * 512], 16, 0, 0);
      __builtin_amdgcn_global_load_lds((as1_cu32*)gb[u], (as3_u32*)&Bs[i * 512], 16, 0, 0);
      ga[u] += 64; gb[u] += 64;
    }
    __syncthreads();
#pragma unroll
    for (int ks = 0; ks < 2; ks++) {
      s8v af[4], bf[4];
#pragma unroll
      for (int mi = 0; mi < 4; mi++)
        af[mi] = *(const s8v*)&As[(((wm + mi) * 2 + ks) * 64 + L) * 8];
#pragma unroll
      for (int ni = 0; ni < 4; ni++)
        bf[ni] = *(const s8v*)&Bs[(((wn + ni) * 2 + ks) * 64 + L) * 8];
#pragma unroll
      for (int mi = 0; mi < 4; mi++)
#pragma unroll
        for (int ni = 0; ni < 4; ni++)
          acc[mi][ni] = __builtin_amdgcn_mfma_f32_16x16x32_bf16(af[mi], bf[ni], acc[mi][ni], 0, 0, 0);
    }
    __syncthreads();
  }
#pragma unroll
  for (int ni = 0; ni < 4; ni++) {
    int col = bn + (wn + ni) * 16 + (L & 15);
    float bb = bias ? bias[col] : 0.f;
#pragma unroll
    for (int mi = 0; mi < 4; mi++) {
      int rbase = bm + (wm + mi) * 16 + (L >> 4) * 4;
#pragma unroll
      for (int i = 0; i < 4; i++) {
        int r = rbase + i;
        if (r < M) Out[(size_t)r * ldc + col] = (OutT)(acc[mi][ni][i] + bb);
      }
    }
  }
}

// ---------------------------------------------------------------- attention logits a_s, a_d (fp16 input)
__launch_bounds__(256)
__global__ void k_att(const _Float16* __restrict__ B, const float* __restrict__ asrc,
                      const float* __restrict__ adst,
                      float* __restrict__ as_, float* __restrict__ ad_) {
  int wid = (blockIdx.x * 256 + threadIdx.x) >> 6;  // node
  int lane = threadIdx.x & 63;
  h4v x = *(const h4v*)&B[(size_t)wid * 256 + (lane << 2)];
  float4 s4 = *(const float4*)&asrc[lane << 2];
  float4 d4 = *(const float4*)&adst[lane << 2];
  float x0 = (float)x[0], x1 = (float)x[1], x2 = (float)x[2], x3 = (float)x[3];
  float vs = x0 * s4.x + x1 * s4.y + x2 * s4.z + x3 * s4.w;
  float vd = x0 * d4.x + x1 * d4.y + x2 * d4.z + x3 * d4.w;
  vs += __shfl_xor(vs, 1); vs += __shfl_xor(vs, 2); vs += __shfl_xor(vs, 4);
  vd += __shfl_xor(vd, 1); vd += __shfl_xor(vd, 2); vd += __shfl_xor(vd, 4);
  if ((lane & 7) == 0) {
    as_[wid * NH + (lane >> 3)] = vs;
    ad_[wid * NH + (lane >> 3)] = vd;
  }
}

// ---------------------------------------------------------------- softmax + aggregate + BN stats
// one wave / node; fp16 gather; softmax without max-sub (logits bounded, ratio identical);
// fused per-block BN stats -> global atomics.
__launch_bounds__(256)
__global__ void k_agg(const int* __restrict__ rowptr, const int* __restrict__ srcs,
                      const float* __restrict__ as_, const float* __restrict__ ad_,
                      const _Float16* __restrict__ B, const float* __restrict__ gb,
                      _Float16* __restrict__ C, float* __restrict__ stats) {
  __shared__ float ss[512];
  int t = threadIdx.x;
  ss[t] = 0.f; ss[t + 256] = 0.f;
  __syncthreads();
  int n = (blockIdx.x * 256 + t) >> 6;
  int lane = t & 63;
  int beg = rowptr[n], end = rowptr[n + 1];
  int h = lane >> 3, j = lane & 7;
  float ad_nh = ad_[n * NH + h];
  // phase 1: per-head sum of exp (no max-sub; |e| small by construction)
  float sm = 0.f;
  for (int k = beg + j; k < end; k += 8) {
    int s = srcs[k];
    float e = as_[s * NH + h] + ad_nh;
    e = e > 0.f ? e : 0.2f * e;
    sm += __expf(e);
  }
  sm += __shfl_xor(sm, 1); sm += __shfl_xor(sm, 2); sm += __shfl_xor(sm, 4);
  float inv = 1.f / (sm + 1e-16f);
  // phase 2: gather fp16 rows, fp32 accumulate; unroll x4 for MLP
  int cb = lane << 2;  // 4 channels per lane
  float ac0 = 0.f, ac1 = 0.f, ac2 = 0.f, ac3 = 0.f;
  int k = beg;
  for (; k + 4 <= end; k += 4) {
    int s0 = srcs[k], s1 = srcs[k + 1], s2 = srcs[k + 2], s3 = srcs[k + 3];
    h4v b0 = *(const h4v*)&B[(size_t)s0 * 256 + cb];
    h4v b1 = *(const h4v*)&B[(size_t)s1 * 256 + cb];
    h4v b2 = *(const h4v*)&B[(size_t)s2 * 256 + cb];
    h4v b3 = *(const h4v*)&B[(size_t)s3 * 256 + cb];
    float e0 = as_[s0 * NH + h] + ad_nh; e0 = e0 > 0.f ? e0 : 0.2f * e0;
    float e1 = as_[s1 * NH + h] + ad_nh; e1 = e1 > 0.f ? e1 : 0.2f * e1;
    float e2 = as_[s2 * NH + h] + ad_nh; e2 = e2 > 0.f ? e2 : 0.2f * e2;
    float e3 = as_[s3 * NH + h] + ad_nh; e3 = e3 > 0.f ? e3 : 0.2f * e3;
    float a0 = __expf(e0) * inv, a1 = __expf(e1) * inv;
    float a2 = __expf(e2) * inv, a3 = __expf(e3) * inv;
    ac0 += a0 * (float)b0[0] + a1 * (float)b1[0] + a2 * (float)b2[0] + a3 * (float)b3[0];
    ac1 += a0 * (float)b0[1] + a1 * (float)b1[1] + a2 * (float)b2[1] + a3 * (float)b3[1];
    ac2 += a0 * (float)b0[2] + a1 * (float)b1[2] + a2 * (float)b2[2] + a3 * (float)b3[2];
    ac3 += a0 * (float)b0[3] + a1 * (float)b1[3] + a2 * (float)b2[3] + a3 * (float)b3[3];
  }
  for (; k < end; k++) {
    int s = srcs[k];
    h4v b4 = *(const h4v*)&B[(size_t)s * 256 + cb];
    float e = as_[s * NH + h] + ad_nh;
    e = e > 0.f ? e : 0.2f * e;
    float a = __expf(e) * inv;
    ac0 += a * (float)b4[0]; ac1 += a * (float)b4[1];
    ac2 += a * (float)b4[2]; ac3 += a * (float)b4[3];
  }
  float4 g4 = *(const float4*)&gb[cb];
  float v0 = ac0 + g4.x, v1 = ac1 + g4.y, v2 = ac2 + g4.z, v3 = ac3 + g4.w;
  h4v o; o[0] = (_Float16)v0; o[1] = (_Float16)v1; o[2] = (_Float16)v2; o[3] = (_Float16)v3;
  *(h4v*)&C[(size_t)n * 256 + cb] = o;
  // BN stats: block-level LDS reduce (4 waves hit same channel slots), then global atomics
  atomicAdd(&ss[cb + 0], v0); atomicAdd(&ss[256 + cb + 0], v0 * v0);
  atomicAdd(&ss[cb + 1], v1); atomicAdd(&ss[256 + cb + 1], v1 * v1);
  atomicAdd(&ss[cb + 2], v2); atomicAdd(&ss[256 + cb + 2], v2 * v2);
  atomicAdd(&ss[cb + 3], v3); atomicAdd(&ss[256 + cb + 3], v3 * v3);
  __syncthreads();
  atomicAdd(&stats[t], ss[t]);
  atomicAdd(&stats[t + 256], ss[t + 256]);
}

// BN + ReLU (+ optional residual add): fp16 in -> bf16 out
__global__ void k_bn_relu_cvt(const _Float16* __restrict__ X, const float* __restrict__ stats,
                              const float* __restrict__ g, const float* __restrict__ b,
                              const float* __restrict__ resid, ushort* __restrict__ Xb) {
  size_t i = ((size_t)blockIdx.x * 256 + threadIdx.x) * 4;
  int c = (int)(i & 255);
  const float invN = 1.f / (float)N_NODES;
  h4v x4 = *(const h4v*)&X[i];
  float4 s4 = *(const float4*)&stats[c];
  float4 q4 = *(const float4*)&stats[256 + c];
  float4 g4 = *(const float4*)&g[c];
  float4 b4 = *(const float4*)&b[c];
  float m0 = s4.x * invN, m1 = s4.y * invN, m2 = s4.z * invN, m3 = s4.w * invN;
  float v0 = ((float)x4[0] - m0) * rsqrtf(q4.x * invN - m0 * m0 + 1e-5f) * g4.x + b4.x;
  float v1 = ((float)x4[1] - m1) * rsqrtf(q4.y * invN - m1 * m1 + 1e-5f) * g4.y + b4.y;
  float v2 = ((float)x4[2] - m2) * rsqrtf(q4.z * invN - m2 * m2 + 1e-5f) * g4.z + b4.z;
  float v3 = ((float)x4[3] - m3) * rsqrtf(q4.w * invN - m3 * m3 + 1e-5f) * g4.w + b4.w;
  v0 = v0 > 0.f ? v0 : 0.f; v1 = v1 > 0.f ? v1 : 0.f;
  v2 = v2 > 0.f ? v2 : 0.f; v3 = v3 > 0.f ? v3 : 0.f;
  if (resid) {
    float4 r4 = *(const float4*)&resid[i];
    v0 += r4.x; v1 += r4.y; v2 += r4.z; v3 += r4.w;
  }
  ushort4 ob;
  ob.x = f2bf(v0); ob.y = f2bf(v1); ob.z = f2bf(v2); ob.w = f2bf(v3);
  *(ushort4*)&Xb[i] = ob;
}

// ---------------------------------------------------------------- decode epilogue (one wave / node)
__launch_bounds__(256)
__global__ void k_dec(const float* __restrict__ Hd, const float* __restrict__ eps,
                      const float* __restrict__ mub, const float* __restrict__ lvb,
                      const float* __restrict__ auxb,
                      const float* __restrict__ decW, const float* __restrict__ decb,
                      float* __restrict__ out) {
  __shared__ float wsd[2048];   // decW [32][64]
  __shared__ float shz[4][32];
  int t = threadIdx.x;
  for (int i = t; i < 2048; i += 256) wsd[i] = decW[i];
  int w = t >> 6, lane = t & 63;
  int n = blockIdx.x * 4 + w;
  const float* hd = &Hd[(size_t)n * 128];
  if (lane < 32) {
    float mu = hd[lane] + mub[lane];
    float lv = hd[32 + lane] + lvb[lane];
    out[(size_t)N_NODES * 64 + (size_t)n * 32 + lane] = mu;
    out[(size_t)N_NODES * 96 + (size_t)n * 32 + lane] = lv;
    shz[w][lane] = mu + eps[(size_t)n * 32 + lane] * __expf(0.5f * lv);
  } else if (lane < 62) {
    int j = lane - 32;
    out[(size_t)N_NODES * 128 + (size_t)n * 30 + j] = hd[64 + j] + auxb[j];
  }
  __syncthreads();
  float o = decb[lane];
#pragma unroll 8
  for (int k = 0; k < 32; k++) o += shz[w][k] * wsd[k * 64 + lane];
  out[(size_t)n * 64 + lane] = o;
}

// ---------------------------------------------------------------- launch
extern "C" void kernel_launch(void* const* d_in, const int* in_sizes, int n_in,
                              void* d_out, int out_size, void* d_ws, size_t ws_size,
                              hipStream_t stream) {
  (void)in_sizes; (void)n_in; (void)out_size; (void)ws_size;
  const float* x    = (const float*)d_in[0];
  const float* eps  = (const float*)d_in[1];
  const int*   ei   = (const int*)d_in[2];
  const float* gW[3]    = {(const float*)d_in[3],  (const float*)d_in[9],  (const float*)d_in[15]};
  const float* gasrc[3] = {(const float*)d_in[4],  (const float*)d_in[10], (const float*)d_in[16]};
  const float* gadst[3] = {(const float*)d_in[5],  (const float*)d_in[11], (const float*)d_in[17]};
  const float* gbias[3] = {(const float*)d_in[6],  (const float*)d_in[12], (const float*)d_in[18]};
  const float* bng[3]   = {(const float*)d_in[7],  (const float*)d_in[13], (const float*)d_in[19]};
  const float* bnb[3]   = {(const float*)d_in[8],  (const float*)d_in[14], (const float*)d_in[20]};
  const float* resW = (const float*)d_in[21];
  const float* resb = (const float*)d_in[22];
  const float* muW  = (const float*)d_in[23];
  const float* mub  = (const float*)d_in[24];
  const float* lvW  = (const float*)d_in[25];
  const float* lvb  = (const float*)d_in[26];
  const float* decW = (const float*)d_in[27];
  const float* decb = (const float*)d_in[28];
  const float* auxW = (const float*)d_in[29];
  const float* auxb = (const float*)d_in[30];
  float* out = (float*)d_out;

  char* ws = (char*)d_ws;
  size_t off = 0;
  auto alloc = [&](size_t bytes) -> void* {
    void* p = ws + off;
    off += (bytes + 255) & ~(size_t)255;
    return p;
  };
  _Float16* X0  = (_Float16*)alloc((size_t)N_NODES * HC * 2);  // GEMM out / att input (fp16)
  _Float16* X1  = (_Float16*)alloc((size_t)N_NODES * HC * 2);  // agg output (fp16)
  float*  Rr    = (float*)alloc((size_t)N_NODES * HC * 4);     // residual (fp32)
  float*  Hd    = (float*)alloc((size_t)N_NODES * 128 * 4);    // head GEMM out (fp32)
  ushort* Xb    = (ushort*)alloc((size_t)N_NODES * HC * 2);    // bf16 activations
  float*  as_   = (float*)alloc((size_t)N_NODES * NH * 4);
  float*  ad_   = (float*)alloc((size_t)N_NODES * NH * 4);
  float*  stats = (float*)alloc(512 * 4);
  int* cnt      = (int*)alloc((size_t)N_NODES * 4);
  int* rowptr   = (int*)alloc((size_t)(N_NODES + 1) * 4);
  int* fillptr  = (int*)alloc((size_t)N_NODES * 4);
  int* srcs     = (int*)alloc((size_t)(N_NODES + N_EDGES) * 4);
  int* bsum     = (int*)alloc(256 * 4);
  ushort* Wt1   = (ushort*)alloc(256 * 128 * 2);
  ushort* Wt2   = (ushort*)alloc(256 * 256 * 2);
  ushort* Wt3   = (ushort*)alloc(256 * 256 * 2);
  ushort* WtR   = (ushort*)alloc(256 * 128 * 2);
  ushort* Wth   = (ushort*)alloc(128 * 256 * 2);

  const int NB = (N_NODES + 255) / 256;
  // CSR build
  k_init_cnt<<<NB, 256, 0, stream>>>(cnt);
  k_count<<<(N_EDGES + 255) / 256, 256, 0, stream>>>(ei + N_EDGES, cnt);
  k_scan_bsum<<<NB, 256, 0, stream>>>(cnt, bsum);
  k_scan_offsets<<<1, 256, 0, stream>>>(bsum, NB);
  k_scan_write<<<NB, 256, 0, stream>>>(cnt, bsum, rowptr, fillptr);
  k_fill<<<(N_NODES + N_EDGES + 255) / 256, 256, 0, stream>>>(ei, ei + N_EDGES, fillptr, srcs);

  // weight prep
  k_cvt_wt<<<dim3(4, 8), 256, 0, stream>>>(gW[0], Wt1, 128, 256);
  k_cvt_wt<<<dim3(8, 8), 256, 0, stream>>>(gW[1], Wt2, 256, 256);
  k_cvt_wt<<<dim3(8, 8), 256, 0, stream>>>(gW[2], Wt3, 256, 256);
  k_cvt_wt<<<dim3(4, 8), 256, 0, stream>>>(resW, WtR, 128, 256);
  k_pack_head<<<128, 256, 0, stream>>>(muW, lvW, auxW, Wth);
  // x -> bf16
  k_cvt_x<<<(N_NODES * 128) / 1024, 256, 0, stream>>>(x, Xb);

  const int GM = (N_NODES + 127) / 128;  // 391
  // residual = x @ res_W + res_b (fp32 out)
  k_gemm_bf16<float><<<dim3(GM, 2), 256, 0, stream>>>(Xb, WtR, resb, Rr, N_NODES, 128, 256);

  const ushort* Wts[3] = {Wt1, Wt2, Wt3};
  int K = 128;
  for (int L = 0; L < 3; L++) {
    k_gemm_bf16<_Float16><<<dim3(GM, 2), 256, 0, stream>>>(Xb, Wts[L], nullptr, X0, N_NODES, K, 256);
    k_att<<<N_NODES / 4, 256, 0, stream>>>(X0, gasrc[L], gadst[L], as_, ad_);
    hipMemsetAsync(stats, 0, 512 * 4, stream);
    k_agg<<<N_NODES / 4, 256, 0, stream>>>(rowptr, srcs, as_, ad_, X0, gbias[L], X1, stats);
    k_bn_relu_cvt<<<(N_NODES * HC) / 1024, 256, 0, stream>>>(
        X1, stats, bng[L], bnb[L], (L == 2) ? Rr : nullptr, Xb);
    K = 256;
  }
  // heads: Hd = h @ [muW|lvW|auxW|0] (fp32 out)
  k_gemm_bf16<float><<<dim3(GM, 1), 256, 0, stream>>>(Xb, Wth, nullptr, Hd, N_NODES, 256, 128);
  k_dec<<<N_NODES / 4, 256, 0, stream>>>(Hd, eps, mub, lvb, auxb, decW, decb, out);
}

// Round 5
// 666.011 us; speedup vs baseline: 2.2124x; 2.2124x over previous
//
#include <hip/hip_runtime.h>

#define N_NODES 50000
#define N_EDGES 600000
#define HC 256
#define NH 8
#define AGG_BLOCKS 1536
#define AGG_WAVES (AGG_BLOCKS * 4)

typedef short s8v __attribute__((ext_vector_type(8)));
typedef float f4v __attribute__((ext_vector_type(4)));
typedef _Float16 h4v __attribute__((ext_vector_type(4)));
typedef __attribute__((address_space(1))) const unsigned int as1_cu32;
typedef __attribute__((address_space(3))) unsigned int as3_u32;

__device__ inline ushort f2bf(float f) {
  unsigned u = __float_as_uint(f);
  unsigned r = u + 0x7FFF + ((u >> 16) & 1);  // RNE
  return (ushort)(r >> 16);
}

// ---------------------------------------------------------------- CSR build
__global__ void k_init_cnt(int* __restrict__ cnt) {
  int i = blockIdx.x * 256 + threadIdx.x;
  if (i < N_NODES) cnt[i] = 1;  // self-loop
}

__global__ void k_count(const int* __restrict__ dstE, int* __restrict__ cnt) {
  int e = blockIdx.x * 256 + threadIdx.x;
  if (e < N_EDGES) atomicAdd(&cnt[dstE[e]], 1);
}

__global__ void k_scan_bsum(const int* __restrict__ cnt, int* __restrict__ bsum) {
  __shared__ int sd[256];
  int i = blockIdx.x * 256 + threadIdx.x;
  sd[threadIdx.x] = (i < N_NODES) ? cnt[i] : 0;
  __syncthreads();
  for (int o = 128; o > 0; o >>= 1) {
    if (threadIdx.x < o) sd[threadIdx.x] += sd[threadIdx.x + o];
    __syncthreads();
  }
  if (threadIdx.x == 0) bsum[blockIdx.x] = sd[0];
}

__global__ void k_scan_offsets(int* __restrict__ bsum, int nb) {
  __shared__ int s[256];
  int t = threadIdx.x;
  int v = (t < nb) ? bsum[t] : 0;
  s[t] = v; __syncthreads();
  for (int o = 1; o < 256; o <<= 1) {
    int x = (t >= o) ? s[t - o] : 0;
    __syncthreads();
    s[t] += x;
    __syncthreads();
  }
  if (t < nb) bsum[t] = s[t] - v;  // exclusive
}

__global__ void k_scan_write(const int* __restrict__ cnt, const int* __restrict__ bsum,
                             int* __restrict__ rowptr, int* __restrict__ fillptr) {
  __shared__ int s[256];
  int t = threadIdx.x;
  int i = blockIdx.x * 256 + t;
  int v = (i < N_NODES) ? cnt[i] : 0;
  s[t] = v; __syncthreads();
  for (int o = 1; o < 256; o <<= 1) {
    int x = (t >= o) ? s[t - o] : 0;
    __syncthreads();
    s[t] += x;
    __syncthreads();
  }
  int excl = s[t] - v + bsum[blockIdx.x];
  if (i < N_NODES) {
    rowptr[i] = excl;
    fillptr[i] = excl;
    if (i == N_NODES - 1) rowptr[N_NODES] = excl + v;
  }
}

__global__ void k_fill(const int* __restrict__ srcE, const int* __restrict__ dstE,
                       int* __restrict__ fillptr, int* __restrict__ srcs) {
  int i = blockIdx.x * 256 + threadIdx.x;
  if (i < N_NODES) {
    int pos = atomicAdd(&fillptr[i], 1);
    srcs[pos] = i;                       // self-loop
  } else if (i < N_NODES + N_EDGES) {
    int e = i - N_NODES;
    int pos = atomicAdd(&fillptr[dstE[e]], 1);
    srcs[pos] = srcE[e];
  }
}

// ---------------------------------------------------------------- fp32 -> bf16 converts
__global__ void k_cvt_x(const float* __restrict__ X, ushort* __restrict__ Xb) {
  size_t i = ((size_t)blockIdx.x * 256 + threadIdx.x) * 4;
  float4 x4 = *(const float4*)&X[i];
  ushort4 o;
  o.x = f2bf(x4.x); o.y = f2bf(x4.y); o.z = f2bf(x4.z); o.w = f2bf(x4.w);
  *(ushort4*)&Xb[i] = o;
}

// W[K][Nw] fp32 -> Wt[Nw][K] bf16 (transpose + convert)
__global__ void k_cvt_wt(const float* __restrict__ W, ushort* __restrict__ Wt, int K, int Nw) {
  __shared__ ushort s[32][33];
  int tx = threadIdx.x & 31, ty = threadIdx.x >> 5;
  int k0 = blockIdx.x * 32, n0 = blockIdx.y * 32;
  for (int j = 0; j < 32; j += 8)
    s[ty + j][tx] = f2bf(W[(size_t)(k0 + ty + j) * Nw + n0 + tx]);
  __syncthreads();
  for (int j = 0; j < 32; j += 8)
    Wt[(size_t)(n0 + ty + j) * K + k0 + tx] = s[tx][ty + j];
}

// pack [muW | lvW | auxW | 0] -> Wth[128][256] bf16
__global__ void k_pack_head(const float* __restrict__ muW, const float* __restrict__ lvW,
                            const float* __restrict__ auxW, ushort* __restrict__ Wth) {
  int n = blockIdx.x;   // 0..127
  int k = threadIdx.x;  // 0..255
  float v = 0.f;
  if (n < 32) v = muW[k * 32 + n];
  else if (n < 64) v = lvW[k * 32 + (n - 32)];
  else if (n < 94) v = auxW[k * 30 + (n - 64)];
  Wth[n * 256 + k] = f2bf(v);
}

// ---------------------------------------------------------------- bf16 MFMA GEMM (m97-style)
template <typename OutT>
__launch_bounds__(256)
__global__ void k_gemm_bf16(const ushort* __restrict__ A, const ushort* __restrict__ Wt,
                            const float* __restrict__ bias, OutT* __restrict__ Out,
                            int M, int K, int ldc) {
  __shared__ __align__(16) ushort As[16 * 512];  // 16 KB
  __shared__ __align__(16) ushort Bs[16 * 512];  // 16 KB
  int t = threadIdx.x, w = t >> 6, L = t & 63;
  int bm = blockIdx.x * 128, bn = blockIdx.y * 128;
  int lrow = L & 15, lcol = (L >> 4) * 8;

  const ushort* ga[4];
  const ushort* gb[4];
#pragma unroll
  for (int u = 0; u < 4; u++) {
    int i = w * 4 + u;
    int mt = i >> 1, ks = i & 1;
    int arow = bm + mt * 16 + lrow;
    if (arow >= M) arow = M - 1;
    ga[u] = A + (size_t)arow * K + ks * 32 + lcol;
    int brow = bn + mt * 16 + lrow;
    gb[u] = Wt + (size_t)brow * K + ks * 32 + lcol;
  }

  f4v acc[4][4];
  f4v zero = {0.f, 0.f, 0.f, 0.f};
#pragma unroll
  for (int mi = 0; mi < 4; mi++)
#pragma unroll
    for (int ni = 0; ni < 4; ni++) acc[mi][ni] = zero;

  int wm = (w >> 1) * 4;
  int wn = (w & 1) * 4;

  int nk = K >> 6;
  for (int kt = 0; kt < nk; kt++) {
#pragma unroll
    for (int u = 0; u < 4; u++) {
      int i = w * 4 + u;
      __builtin_amdgcn_global_load_lds((as1_cu32*)ga[u], (as3_u32*)&As[i * 512], 16, 0, 0);
      __builtin_amdgcn_global_load_lds((as1_cu32*)gb[u], (as3_u32*)&Bs[i * 512], 16, 0, 0);
      ga[u] += 64; gb[u] += 64;
    }
    __syncthreads();
#pragma unroll
    for (int ks = 0; ks < 2; ks++) {
      s8v af[4], bf[4];
#pragma unroll
      for (int mi = 0; mi < 4; mi++)
        af[mi] = *(const s8v*)&As[(((wm + mi) * 2 + ks) * 64 + L) * 8];
#pragma unroll
      for (int ni = 0; ni < 4; ni++)
        bf[ni] = *(const s8v*)&Bs[(((wn + ni) * 2 + ks) * 64 + L) * 8];
#pragma unroll
      for (int mi = 0; mi < 4; mi++)
#pragma unroll
        for (int ni = 0; ni < 4; ni++)
          acc[mi][ni] = __builtin_amdgcn_mfma_f32_16x16x32_bf16(af[mi], bf[ni], acc[mi][ni], 0, 0, 0);
    }
    __syncthreads();
  }
#pragma unroll
  for (int ni = 0; ni < 4; ni++) {
    int col = bn + (wn + ni) * 16 + (L & 15);
    float bb = bias ? bias[col] : 0.f;
#pragma unroll
    for (int mi = 0; mi < 4; mi++) {
      int rbase = bm + (wm + mi) * 16 + (L >> 4) * 4;
#pragma unroll
      for (int i = 0; i < 4; i++) {
        int r = rbase + i;
        if (r < M) Out[(size_t)r * ldc + col] = (OutT)(acc[mi][ni][i] + bb);
      }
    }
  }
}

// ---------------------------------------------------------------- attention logits a_s, a_d (fp16 input)
__launch_bounds__(256)
__global__ void k_att(const _Float16* __restrict__ B, const float* __restrict__ asrc,
                      const float* __restrict__ adst,
                      float* __restrict__ as_, float* __restrict__ ad_) {
  int wid = (blockIdx.x * 256 + threadIdx.x) >> 6;  // node
  int lane = threadIdx.x & 63;
  h4v x = *(const h4v*)&B[(size_t)wid * 256 + (lane << 2)];
  float4 s4 = *(const float4*)&asrc[lane << 2];
  float4 d4 = *(const float4*)&adst[lane << 2];
  float x0 = (float)x[0], x1 = (float)x[1], x2 = (float)x[2], x3 = (float)x[3];
  float vs = x0 * s4.x + x1 * s4.y + x2 * s4.z + x3 * s4.w;
  float vd = x0 * d4.x + x1 * d4.y + x2 * d4.z + x3 * d4.w;
  vs += __shfl_xor(vs, 1); vs += __shfl_xor(vs, 2); vs += __shfl_xor(vs, 4);
  vd += __shfl_xor(vd, 1); vd += __shfl_xor(vd, 2); vd += __shfl_xor(vd, 4);
  if ((lane & 7) == 0) {
    as_[wid * NH + (lane >> 3)] = vs;
    ad_[wid * NH + (lane >> 3)] = vd;
  }
}

// ---------------------------------------------------------------- softmax + aggregate + BN partials
// persistent grid (AGG_BLOCKS blocks, grid-stride over nodes, one wave / node).
// BN stats accumulated in registers, LDS-reduced per block, PLAIN-STORED as partials
// (no high-contention atomics — that was round 4's 3x regression).
__launch_bounds__(256)
__global__ void k_agg(const int* __restrict__ rowptr, const int* __restrict__ srcs,
                      const float* __restrict__ as_, const float* __restrict__ ad_,
                      const _Float16* __restrict__ B, const float* __restrict__ gb,
                      _Float16* __restrict__ C, float* __restrict__ part) {
  __shared__ float ss[4 * 512];
  int t = threadIdx.x;
  int w = t >> 6, lane = t & 63;
  int h = lane >> 3, j = lane & 7;
  int cb = lane << 2;  // 4 channels per lane
  float4 g4 = *(const float4*)&gb[cb];
  float sts0 = 0.f, sts1 = 0.f, sts2 = 0.f, sts3 = 0.f;
  float stq0 = 0.f, stq1 = 0.f, stq2 = 0.f, stq3 = 0.f;

  for (int n = blockIdx.x * 4 + w; n < N_NODES; n += AGG_WAVES) {
    int beg = rowptr[n], end = rowptr[n + 1];
    float ad_nh = ad_[n * NH + h];
    // phase 1: per-head sum of exp (no max-sub; logits bounded)
    float sm = 0.f;
    for (int k = beg + j; k < end; k += 8) {
      int s = srcs[k];
      float e = as_[s * NH + h] + ad_nh;
      e = e > 0.f ? e : 0.2f * e;
      sm += __expf(e);
    }
    sm += __shfl_xor(sm, 1); sm += __shfl_xor(sm, 2); sm += __shfl_xor(sm, 4);
    float inv = 1.f / (sm + 1e-16f);
    // phase 2: fp16 gather, fp32 accumulate, unroll x4 for MLP
    float ac0 = 0.f, ac1 = 0.f, ac2 = 0.f, ac3 = 0.f;
    int k = beg;
    for (; k + 4 <= end; k += 4) {
      int s0 = srcs[k], s1 = srcs[k + 1], s2 = srcs[k + 2], s3 = srcs[k + 3];
      h4v b0 = *(const h4v*)&B[(size_t)s0 * 256 + cb];
      h4v b1 = *(const h4v*)&B[(size_t)s1 * 256 + cb];
      h4v b2 = *(const h4v*)&B[(size_t)s2 * 256 + cb];
      h4v b3 = *(const h4v*)&B[(size_t)s3 * 256 + cb];
      float e0 = as_[s0 * NH + h] + ad_nh; e0 = e0 > 0.f ? e0 : 0.2f * e0;
      float e1 = as_[s1 * NH + h] + ad_nh; e1 = e1 > 0.f ? e1 : 0.2f * e1;
      float e2 = as_[s2 * NH + h] + ad_nh; e2 = e2 > 0.f ? e2 : 0.2f * e2;
      float e3 = as_[s3 * NH + h] + ad_nh; e3 = e3 > 0.f ? e3 : 0.2f * e3;
      float a0 = __expf(e0) * inv, a1 = __expf(e1) * inv;
      float a2 = __expf(e2) * inv, a3 = __expf(e3) * inv;
      ac0 += a0 * (float)b0[0] + a1 * (float)b1[0] + a2 * (float)b2[0] + a3 * (float)b3[0];
      ac1 += a0 * (float)b0[1] + a1 * (float)b1[1] + a2 * (float)b2[1] + a3 * (float)b3[1];
      ac2 += a0 * (float)b0[2] + a1 * (float)b1[2] + a2 * (float)b2[2] + a3 * (float)b3[2];
      ac3 += a0 * (float)b0[3] + a1 * (float)b1[3] + a2 * (float)b2[3] + a3 * (float)b3[3];
    }
    for (; k < end; k++) {
      int s = srcs[k];
      h4v b4 = *(const h4v*)&B[(size_t)s * 256 + cb];
      float e = as_[s * NH + h] + ad_nh;
      e = e > 0.f ? e : 0.2f * e;
      float a = __expf(e) * inv;
      ac0 += a * (float)b4[0]; ac1 += a * (float)b4[1];
      ac2 += a * (float)b4[2]; ac3 += a * (float)b4[3];
    }
    float v0 = ac0 + g4.x, v1 = ac1 + g4.y, v2 = ac2 + g4.z, v3 = ac3 + g4.w;
    h4v o; o[0] = (_Float16)v0; o[1] = (_Float16)v1; o[2] = (_Float16)v2; o[3] = (_Float16)v3;
    *(h4v*)&C[(size_t)n * 256 + cb] = o;
    sts0 += v0; stq0 += v0 * v0;
    sts1 += v1; stq1 += v1 * v1;
    sts2 += v2; stq2 += v2 * v2;
    sts3 += v3; stq3 += v3 * v3;
  }
  // per-wave LDS slots (no atomics), then cross-wave sum, plain store of partials
  float* sw = &ss[w * 512];
  sw[cb + 0] = sts0; sw[cb + 1] = sts1; sw[cb + 2] = sts2; sw[cb + 3] = sts3;
  sw[256 + cb + 0] = stq0; sw[256 + cb + 1] = stq1;
  sw[256 + cb + 2] = stq2; sw[256 + cb + 3] = stq3;
  __syncthreads();
  float p0 = ss[t] + ss[512 + t] + ss[1024 + t] + ss[1536 + t];
  float p1 = ss[256 + t] + ss[768 + t] + ss[1280 + t] + ss[1792 + t];
  part[(size_t)blockIdx.x * 512 + t] = p0;
  part[(size_t)blockIdx.x * 512 + 256 + t] = p1;
}

// reduce AGG_BLOCKS x 512 partials -> stats[512]; 16 blocks x 96 rows, tiny atomic fan-in
__global__ void k_bn_reduce(const float* __restrict__ part, float* __restrict__ stats) {
  int i = threadIdx.x;            // 0..255
  int base = blockIdx.x * (AGG_BLOCKS / 16);
  float s0 = 0.f, s1 = 0.f;
  for (int b = 0; b < AGG_BLOCKS / 16; b++) {
    s0 += part[(size_t)(base + b) * 512 + i];
    s1 += part[(size_t)(base + b) * 512 + 256 + i];
  }
  atomicAdd(&stats[i], s0);
  atomicAdd(&stats[256 + i], s1);
}

// BN + ReLU (+ optional residual add): fp16 in -> bf16 out
__global__ void k_bn_relu_cvt(const _Float16* __restrict__ X, const float* __restrict__ stats,
                              const float* __restrict__ g, const float* __restrict__ b,
                              const float* __restrict__ resid, ushort* __restrict__ Xb) {
  size_t i = ((size_t)blockIdx.x * 256 + threadIdx.x) * 4;
  int c = (int)(i & 255);
  const float invN = 1.f / (float)N_NODES;
  h4v x4 = *(const h4v*)&X[i];
  float4 s4 = *(const float4*)&stats[c];
  float4 q4 = *(const float4*)&stats[256 + c];
  float4 g4 = *(const float4*)&g[c];
  float4 b4 = *(const float4*)&b[c];
  float m0 = s4.x * invN, m1 = s4.y * invN, m2 = s4.z * invN, m3 = s4.w * invN;
  float v0 = ((float)x4[0] - m0) * rsqrtf(q4.x * invN - m0 * m0 + 1e-5f) * g4.x + b4.x;
  float v1 = ((float)x4[1] - m1) * rsqrtf(q4.y * invN - m1 * m1 + 1e-5f) * g4.y + b4.y;
  float v2 = ((float)x4[2] - m2) * rsqrtf(q4.z * invN - m2 * m2 + 1e-5f) * g4.z + b4.z;
  float v3 = ((float)x4[3] - m3) * rsqrtf(q4.w * invN - m3 * m3 + 1e-5f) * g4.w + b4.w;
  v0 = v0 > 0.f ? v0 : 0.f; v1 = v1 > 0.f ? v1 : 0.f;
  v2 = v2 > 0.f ? v2 : 0.f; v3 = v3 > 0.f ? v3 : 0.f;
  if (resid) {
    float4 r4 = *(const float4*)&resid[i];
    v0 += r4.x; v1 += r4.y; v2 += r4.z; v3 += r4.w;
  }
  ushort4 ob;
  ob.x = f2bf(v0); ob.y = f2bf(v1); ob.z = f2bf(v2); ob.w = f2bf(v3);
  *(ushort4*)&Xb[i] = ob;
}

// ---------------------------------------------------------------- decode epilogue (one wave / node)
__launch_bounds__(256)
__global__ void k_dec(const float* __restrict__ Hd, const float* __restrict__ eps,
                      const float* __restrict__ mub, const float* __restrict__ lvb,
                      const float* __restrict__ auxb,
                      const float* __restrict__ decW, const float* __restrict__ decb,
                      float* __restrict__ out) {
  __shared__ float wsd[2048];   // decW [32][64]
  __shared__ float shz[4][32];
  int t = threadIdx.x;
  for (int i = t; i < 2048; i += 256) wsd[i] = decW[i];
  int w = t >> 6, lane = t & 63;
  int n = blockIdx.x * 4 + w;
  const float* hd = &Hd[(size_t)n * 128];
  if (lane < 32) {
    float mu = hd[lane] + mub[lane];
    float lv = hd[32 + lane] + lvb[lane];
    out[(size_t)N_NODES * 64 + (size_t)n * 32 + lane] = mu;
    out[(size_t)N_NODES * 96 + (size_t)n * 32 + lane] = lv;
    shz[w][lane] = mu + eps[(size_t)n * 32 + lane] * __expf(0.5f * lv);
  } else if (lane < 62) {
    int j = lane - 32;
    out[(size_t)N_NODES * 128 + (size_t)n * 30 + j] = hd[64 + j] + auxb[j];
  }
  __syncthreads();
  float o = decb[lane];
#pragma unroll 8
  for (int k = 0; k < 32; k++) o += shz[w][k] * wsd[k * 64 + lane];
  out[(size_t)n * 64 + lane] = o;
}

// ---------------------------------------------------------------- launch
extern "C" void kernel_launch(void* const* d_in, const int* in_sizes, int n_in,
                              void* d_out, int out_size, void* d_ws, size_t ws_size,
                              hipStream_t stream) {
  (void)in_sizes; (void)n_in; (void)out_size; (void)ws_size;
  const float* x    = (const float*)d_in[0];
  const float* eps  = (const float*)d_in[1];
  const int*   ei   = (const int*)d_in[2];
  const float* gW[3]    = {(const float*)d_in[3],  (const float*)d_in[9],  (const float*)d_in[15]};
  const float* gasrc[3] = {(const float*)d_in[4],  (const float*)d_in[10], (const float*)d_in[16]};
  const float* gadst[3] = {(const float*)d_in[5],  (const float*)d_in[11], (const float*)d_in[17]};
  const float* gbias[3] = {(const float*)d_in[6],  (const float*)d_in[12], (const float*)d_in[18]};
  const float* bng[3]   = {(const float*)d_in[7],  (const float*)d_in[13], (const float*)d_in[19]};
  const float* bnb[3]   = {(const float*)d_in[8],  (const float*)d_in[14], (const float*)d_in[20]};
  const float* resW = (const float*)d_in[21];
  const float* resb = (const float*)d_in[22];
  const float* muW  = (const float*)d_in[23];
  const float* mub  = (const float*)d_in[24];
  const float* lvW  = (const float*)d_in[25];
  const float* lvb  = (const float*)d_in[26];
  const float* decW = (const float*)d_in[27];
  const float* decb = (const float*)d_in[28];
  const float* auxW = (const float*)d_in[29];
  const float* auxb = (const float*)d_in[30];
  float* out = (float*)d_out;

  char* ws = (char*)d_ws;
  size_t off = 0;
  auto alloc = [&](size_t bytes) -> void* {
    void* p = ws + off;
    off += (bytes + 255) & ~(size_t)255;
    return p;
  };
  _Float16* X0  = (_Float16*)alloc((size_t)N_NODES * HC * 2);  // GEMM out / att input (fp16)
  _Float16* X1  = (_Float16*)alloc((size_t)N_NODES * HC * 2);  // agg output (fp16)
  float*  Rr    = (float*)alloc((size_t)N_NODES * HC * 4);     // residual (fp32)
  float*  Hd    = (float*)alloc((size_t)N_NODES * 128 * 4);    // head GEMM out (fp32)
  ushort* Xb    = (ushort*)alloc((size_t)N_NODES * HC * 2);    // bf16 activations
  float*  as_   = (float*)alloc((size_t)N_NODES * NH * 4);
  float*  ad_   = (float*)alloc((size_t)N_NODES * NH * 4);
  float*  stats = (float*)alloc(512 * 4);
  float*  part  = (float*)alloc((size_t)AGG_BLOCKS * 512 * 4); // 3 MB BN partials
  int* cnt      = (int*)alloc((size_t)N_NODES * 4);
  int* rowptr   = (int*)alloc((size_t)(N_NODES + 1) * 4);
  int* fillptr  = (int*)alloc((size_t)N_NODES * 4);
  int* srcs     = (int*)alloc((size_t)(N_NODES + N_EDGES) * 4);
  int* bsum     = (int*)alloc(256 * 4);
  ushort* Wt1   = (ushort*)alloc(256 * 128 * 2);
  ushort* Wt2   = (ushort*)alloc(256 * 256 * 2);
  ushort* Wt3   = (ushort*)alloc(256 * 256 * 2);
  ushort* WtR   = (ushort*)alloc(256 * 128 * 2);
  ushort* Wth   = (ushort*)alloc(128 * 256 * 2);

  const int NB = (N_NODES + 255) / 256;
  // CSR build
  k_init_cnt<<<NB, 256, 0, stream>>>(cnt);
  k_count<<<(N_EDGES + 255) / 256, 256, 0, stream>>>(ei + N_EDGES, cnt);
  k_scan_bsum<<<NB, 256, 0, stream>>>(cnt, bsum);
  k_scan_offsets<<<1, 256, 0, stream>>>(bsum, NB);
  k_scan_write<<<NB, 256, 0, stream>>>(cnt, bsum, rowptr, fillptr);
  k_fill<<<(N_NODES + N_EDGES + 255) / 256, 256, 0, stream>>>(ei, ei + N_EDGES, fillptr, srcs);

  // weight prep
  k_cvt_wt<<<dim3(4, 8), 256, 0, stream>>>(gW[0], Wt1, 128, 256);
  k_cvt_wt<<<dim3(8, 8), 256, 0, stream>>>(gW[1], Wt2, 256, 256);
  k_cvt_wt<<<dim3(8, 8), 256, 0, stream>>>(gW[2], Wt3, 256, 256);
  k_cvt_wt<<<dim3(4, 8), 256, 0, stream>>>(resW, WtR, 128, 256);
  k_pack_head<<<128, 256, 0, stream>>>(muW, lvW, auxW, Wth);
  // x -> bf16
  k_cvt_x<<<(N_NODES * 128) / 1024, 256, 0, stream>>>(x, Xb);

  const int GM = (N_NODES + 127) / 128;  // 391
  // residual = x @ res_W + res_b (fp32 out)
  k_gemm_bf16<float><<<dim3(GM, 2), 256, 0, stream>>>(Xb, WtR, resb, Rr, N_NODES, 128, 256);

  const ushort* Wts[3] = {Wt1, Wt2, Wt3};
  int K = 128;
  for (int L = 0; L < 3; L++) {
    k_gemm_bf16<_Float16><<<dim3(GM, 2), 256, 0, stream>>>(Xb, Wts[L], nullptr, X0, N_NODES, K, 256);
    k_att<<<N_NODES / 4, 256, 0, stream>>>(X0, gasrc[L], gadst[L], as_, ad_);
    k_agg<<<AGG_BLOCKS, 256, 0, stream>>>(rowptr, srcs, as_, ad_, X0, gbias[L], X1, part);
    hipMemsetAsync(stats, 0, 512 * 4, stream);
    k_bn_reduce<<<16, 256, 0, stream>>>(part, stats);
    k_bn_relu_cvt<<<(N_NODES * HC) / 1024, 256, 0, stream>>>(
        X1, stats, bng[L], bnb[L], (L == 2) ? Rr : nullptr, Xb);
    K = 256;
  }
  // heads: Hd = h @ [muW|lvW|auxW|0] (fp32 out)
  k_gemm_bf16<float><<<dim3(GM, 1), 256, 0, stream>>>(Xb, Wth, nullptr, Hd, N_NODES, 256, 128);
  k_dec<<<N_NODES / 4, 256, 0, stream>>>(Hd, eps, mub, lvb, auxb, decW, decb, out);
}

// Round 6
// 651.935 us; speedup vs baseline: 2.2601x; 1.0216x over previous
//
#include <hip/hip_runtime.h>

#define N_NODES 50000
#define N_EDGES 600000
#define HC 256
#define NH 8
#define AGG_BLOCKS 2048
#define AGG_WAVES (AGG_BLOCKS * 4)

typedef short s8v __attribute__((ext_vector_type(8)));
typedef float f4v __attribute__((ext_vector_type(4)));
typedef _Float16 h4v __attribute__((ext_vector_type(4)));
typedef __attribute__((address_space(1))) const unsigned int as1_cu32;
typedef __attribute__((address_space(3))) unsigned int as3_u32;

__device__ inline ushort f2bf(float f) {
  unsigned u = __float_as_uint(f);
  unsigned r = u + 0x7FFF + ((u >> 16) & 1);  // RNE
  return (ushort)(r >> 16);
}

// ---------------------------------------------------------------- CSR build
__global__ void k_init_cnt(int* __restrict__ cnt) {
  int i = blockIdx.x * 256 + threadIdx.x;
  if (i < N_NODES) cnt[i] = 1;  // self-loop
}

__global__ void k_count(const int* __restrict__ dstE, int* __restrict__ cnt) {
  int e = blockIdx.x * 256 + threadIdx.x;
  if (e < N_EDGES) atomicAdd(&cnt[dstE[e]], 1);
}

__global__ void k_scan_bsum(const int* __restrict__ cnt, int* __restrict__ bsum) {
  __shared__ int sd[256];
  int i = blockIdx.x * 256 + threadIdx.x;
  sd[threadIdx.x] = (i < N_NODES) ? cnt[i] : 0;
  __syncthreads();
  for (int o = 128; o > 0; o >>= 1) {
    if (threadIdx.x < o) sd[threadIdx.x] += sd[threadIdx.x + o];
    __syncthreads();
  }
  if (threadIdx.x == 0) bsum[blockIdx.x] = sd[0];
}

__global__ void k_scan_offsets(int* __restrict__ bsum, int nb) {
  __shared__ int s[256];
  int t = threadIdx.x;
  int v = (t < nb) ? bsum[t] : 0;
  s[t] = v; __syncthreads();
  for (int o = 1; o < 256; o <<= 1) {
    int x = (t >= o) ? s[t - o] : 0;
    __syncthreads();
    s[t] += x;
    __syncthreads();
  }
  if (t < nb) bsum[t] = s[t] - v;  // exclusive
}

__global__ void k_scan_write(const int* __restrict__ cnt, const int* __restrict__ bsum,
                             int* __restrict__ rowptr, int* __restrict__ fillptr) {
  __shared__ int s[256];
  int t = threadIdx.x;
  int i = blockIdx.x * 256 + t;
  int v = (i < N_NODES) ? cnt[i] : 0;
  s[t] = v; __syncthreads();
  for (int o = 1; o < 256; o <<= 1) {
    int x = (t >= o) ? s[t - o] : 0;
    __syncthreads();
    s[t] += x;
    __syncthreads();
  }
  int excl = s[t] - v + bsum[blockIdx.x];
  if (i < N_NODES) {
    rowptr[i] = excl;
    fillptr[i] = excl;
    if (i == N_NODES - 1) rowptr[N_NODES] = excl + v;
  }
}

__global__ void k_fill(const int* __restrict__ srcE, const int* __restrict__ dstE,
                       int* __restrict__ fillptr, int* __restrict__ srcs) {
  int i = blockIdx.x * 256 + threadIdx.x;
  if (i < N_NODES) {
    int pos = atomicAdd(&fillptr[i], 1);
    srcs[pos] = i;                       // self-loop
  } else if (i < N_NODES + N_EDGES) {
    int e = i - N_NODES;
    int pos = atomicAdd(&fillptr[dstE[e]], 1);
    srcs[pos] = srcE[e];
  }
}

// ---------------------------------------------------------------- fp32 -> bf16 converts
__global__ void k_cvt_x(const float* __restrict__ X, ushort* __restrict__ Xb) {
  size_t i = ((size_t)blockIdx.x * 256 + threadIdx.x) * 4;
  float4 x4 = *(const float4*)&X[i];
  ushort4 o;
  o.x = f2bf(x4.x); o.y = f2bf(x4.y); o.z = f2bf(x4.z); o.w = f2bf(x4.w);
  *(ushort4*)&Xb[i] = o;
}

// W[K][Nw] fp32 -> Wt[Nw][K] bf16 (transpose + convert)
__global__ void k_cvt_wt(const float* __restrict__ W, ushort* __restrict__ Wt, int K, int Nw) {
  __shared__ ushort s[32][33];
  int tx = threadIdx.x & 31, ty = threadIdx.x >> 5;
  int k0 = blockIdx.x * 32, n0 = blockIdx.y * 32;
  for (int j = 0; j < 32; j += 8)
    s[ty + j][tx] = f2bf(W[(size_t)(k0 + ty + j) * Nw + n0 + tx]);
  __syncthreads();
  for (int j = 0; j < 32; j += 8)
    Wt[(size_t)(n0 + ty + j) * K + k0 + tx] = s[tx][ty + j];
}

// pack [muW | lvW | auxW | 0] -> Wth[128][256] bf16
__global__ void k_pack_head(const float* __restrict__ muW, const float* __restrict__ lvW,
                            const float* __restrict__ auxW, ushort* __restrict__ Wth) {
  int n = blockIdx.x;   // 0..127
  int k = threadIdx.x;  // 0..255
  float v = 0.f;
  if (n < 32) v = muW[k * 32 + n];
  else if (n < 64) v = lvW[k * 32 + (n - 32)];
  else if (n < 94) v = auxW[k * 30 + (n - 64)];
  Wth[n * 256 + k] = f2bf(v);
}

// ---------------------------------------------------------------- bf16 MFMA GEMM (m97-style)
template <typename OutT>
__launch_bounds__(256)
__global__ void k_gemm_bf16(const ushort* __restrict__ A, const ushort* __restrict__ Wt,
                            const float* __restrict__ bias, OutT* __restrict__ Out,
                            int M, int K, int ldc) {
  __shared__ __align__(16) ushort As[16 * 512];  // 16 KB
  __shared__ __align__(16) ushort Bs[16 * 512];  // 16 KB
  int t = threadIdx.x, w = t >> 6, L = t & 63;
  int bm = blockIdx.x * 128, bn = blockIdx.y * 128;
  int lrow = L & 15, lcol = (L >> 4) * 8;

  const ushort* ga[4];
  const ushort* gb[4];
#pragma unroll
  for (int u = 0; u < 4; u++) {
    int i = w * 4 + u;
    int mt = i >> 1, ks = i & 1;
    int arow = bm + mt * 16 + lrow;
    if (arow >= M) arow = M - 1;
    ga[u] = A + (size_t)arow * K + ks * 32 + lcol;
    int brow = bn + mt * 16 + lrow;
    gb[u] = Wt + (size_t)brow * K + ks * 32 + lcol;
  }

  f4v acc[4][4];
  f4v zero = {0.f, 0.f, 0.f, 0.f};
#pragma unroll
  for (int mi = 0; mi < 4; mi++)
#pragma unroll
    for (int ni = 0; ni < 4; ni++) acc[mi][ni] = zero;

  int wm = (w >> 1) * 4;
  int wn = (w & 1) * 4;

  int nk = K >> 6;
  for (int kt = 0; kt < nk; kt++) {
#pragma unroll
    for (int u = 0; u < 4; u++) {
      int i = w * 4 + u;
      __builtin_amdgcn_global_load_lds((as1_cu32*)ga[u], (as3_u32*)&As[i * 512], 16, 0, 0);
      __builtin_amdgcn_global_load_lds((as1_cu32*)gb[u], (as3_u32*)&Bs[i * 512], 16, 0, 0);
      ga[u] += 64; gb[u] += 64;
    }
    __syncthreads();
#pragma unroll
    for (int ks = 0; ks < 2; ks++) {
      s8v af[4], bf[4];
#pragma unroll
      for (int mi = 0; mi < 4; mi++)
        af[mi] = *(const s8v*)&As[(((wm + mi) * 2 + ks) * 64 + L) * 8];
#pragma unroll
      for (int ni = 0; ni < 4; ni++)
        bf[ni] = *(const s8v*)&Bs[(((wn + ni) * 2 + ks) * 64 + L) * 8];
#pragma unroll
      for (int mi = 0; mi < 4; mi++)
#pragma unroll
        for (int ni = 0; ni < 4; ni++)
          acc[mi][ni] = __builtin_amdgcn_mfma_f32_16x16x32_bf16(af[mi], bf[ni], acc[mi][ni], 0, 0, 0);
    }
    __syncthreads();
  }
#pragma unroll
  for (int ni = 0; ni < 4; ni++) {
    int col = bn + (wn + ni) * 16 + (L & 15);
    float bb = bias ? bias[col] : 0.f;
#pragma unroll
    for (int mi = 0; mi < 4; mi++) {
      int rbase = bm + (wm + mi) * 16 + (L >> 4) * 4;
#pragma unroll
      for (int i = 0; i < 4; i++) {
        int r = rbase + i;
        if (r < M) Out[(size_t)r * ldc + col] = (OutT)(acc[mi][ni][i] + bb);
      }
    }
  }
}

// ---------------------------------------------------------------- attention logits a_s, a_d (fp16 input)
__launch_bounds__(256)
__global__ void k_att(const _Float16* __restrict__ B, const float* __restrict__ asrc,
                      const float* __restrict__ adst,
                      float* __restrict__ as_, float* __restrict__ ad_) {
  int wid = (blockIdx.x * 256 + threadIdx.x) >> 6;  // node
  int lane = threadIdx.x & 63;
  h4v x = *(const h4v*)&B[(size_t)wid * 256 + (lane << 2)];
  float4 s4 = *(const float4*)&asrc[lane << 2];
  float4 d4 = *(const float4*)&adst[lane << 2];
  float x0 = (float)x[0], x1 = (float)x[1], x2 = (float)x[2], x3 = (float)x[3];
  float vs = x0 * s4.x + x1 * s4.y + x2 * s4.z + x3 * s4.w;
  float vd = x0 * d4.x + x1 * d4.y + x2 * d4.z + x3 * d4.w;
  vs += __shfl_xor(vs, 1); vs += __shfl_xor(vs, 2); vs += __shfl_xor(vs, 4);
  vd += __shfl_xor(vd, 1); vd += __shfl_xor(vd, 2); vd += __shfl_xor(vd, 4);
  if ((lane & 7) == 0) {
    as_[wid * NH + (lane >> 3)] = vs;
    ad_[wid * NH + (lane >> 3)] = vd;
  }
}

// ---------------------------------------------------------------- aggregate (single pass) + BN partials
// persistent grid; one wave / node. Unnormalized accumulate: acc = sum exp(e)*b,
// wsum = sum exp(e) (identical per lane within a head group), divide once at end.
// Exact same ratio as softmax (max-sub cancels; logits bounded so no overflow).
// BN stats in registers -> per-block plain-stored partials (no hot atomics).
__launch_bounds__(256)
__global__ void k_agg(const int* __restrict__ rowptr, const int* __restrict__ srcs,
                      const float* __restrict__ as_, const float* __restrict__ ad_,
                      const _Float16* __restrict__ B, const float* __restrict__ gb,
                      _Float16* __restrict__ C, float* __restrict__ part,
                      float* __restrict__ stats) {
  __shared__ float ss[4 * 512];
  int t = threadIdx.x;
  if (blockIdx.x == 0) {  // fold stats zeroing (consumed only by k_bn_reduce, after this kernel)
    stats[t] = 0.f; stats[t + 256] = 0.f;
  }
  int w = t >> 6, lane = t & 63;
  int h = lane >> 3;
  int cb = lane << 2;  // 4 channels per lane
  float4 g4 = *(const float4*)&gb[cb];
  float sts0 = 0.f, sts1 = 0.f, sts2 = 0.f, sts3 = 0.f;
  float stq0 = 0.f, stq1 = 0.f, stq2 = 0.f, stq3 = 0.f;

  for (int n = blockIdx.x * 4 + w; n < N_NODES; n += AGG_WAVES) {
    int beg = rowptr[n], end = rowptr[n + 1];
    float ad_nh = ad_[n * NH + h];
    float ac0 = 0.f, ac1 = 0.f, ac2 = 0.f, ac3 = 0.f, wsum = 0.f;
    int k = beg;
    for (; k + 4 <= end; k += 4) {
      int s0 = srcs[k], s1 = srcs[k + 1], s2 = srcs[k + 2], s3 = srcs[k + 3];
      h4v b0 = *(const h4v*)&B[(size_t)s0 * 256 + cb];
      h4v b1 = *(const h4v*)&B[(size_t)s1 * 256 + cb];
      h4v b2 = *(const h4v*)&B[(size_t)s2 * 256 + cb];
      h4v b3 = *(const h4v*)&B[(size_t)s3 * 256 + cb];
      float e0 = as_[s0 * NH + h] + ad_nh; e0 = e0 > 0.f ? e0 : 0.2f * e0;
      float e1 = as_[s1 * NH + h] + ad_nh; e1 = e1 > 0.f ? e1 : 0.2f * e1;
      float e2 = as_[s2 * NH + h] + ad_nh; e2 = e2 > 0.f ? e2 : 0.2f * e2;
      float e3 = as_[s3 * NH + h] + ad_nh; e3 = e3 > 0.f ? e3 : 0.2f * e3;
      float p0 = __expf(e0), p1 = __expf(e1), p2 = __expf(e2), p3 = __expf(e3);
      wsum += (p0 + p1) + (p2 + p3);
      ac0 += p0 * (float)b0[0] + p1 * (float)b1[0] + p2 * (float)b2[0] + p3 * (float)b3[0];
      ac1 += p0 * (float)b0[1] + p1 * (float)b1[1] + p2 * (float)b2[1] + p3 * (float)b3[1];
      ac2 += p0 * (float)b0[2] + p1 * (float)b1[2] + p2 * (float)b2[2] + p3 * (float)b3[2];
      ac3 += p0 * (float)b0[3] + p1 * (float)b1[3] + p2 * (float)b2[3] + p3 * (float)b3[3];
    }
    for (; k < end; k++) {
      int s = srcs[k];
      h4v b4 = *(const h4v*)&B[(size_t)s * 256 + cb];
      float e = as_[s * NH + h] + ad_nh;
      e = e > 0.f ? e : 0.2f * e;
      float p = __expf(e);
      wsum += p;
      ac0 += p * (float)b4[0]; ac1 += p * (float)b4[1];
      ac2 += p * (float)b4[2]; ac3 += p * (float)b4[3];
    }
    float inv = 1.f / (wsum + 1e-16f);
    float v0 = ac0 * inv + g4.x, v1 = ac1 * inv + g4.y;
    float v2 = ac2 * inv + g4.z, v3 = ac3 * inv + g4.w;
    h4v o; o[0] = (_Float16)v0; o[1] = (_Float16)v1; o[2] = (_Float16)v2; o[3] = (_Float16)v3;
    *(h4v*)&C[(size_t)n * 256 + cb] = o;
    sts0 += v0; stq0 += v0 * v0;
    sts1 += v1; stq1 += v1 * v1;
    sts2 += v2; stq2 += v2 * v2;
    sts3 += v3; stq3 += v3 * v3;
  }
  // per-wave LDS slots (no atomics), cross-wave sum, plain store of partials
  float* sw = &ss[w * 512];
  sw[cb + 0] = sts0; sw[cb + 1] = sts1; sw[cb + 2] = sts2; sw[cb + 3] = sts3;
  sw[256 + cb + 0] = stq0; sw[256 + cb + 1] = stq1;
  sw[256 + cb + 2] = stq2; sw[256 + cb + 3] = stq3;
  __syncthreads();
  float p0 = ss[t] + ss[512 + t] + ss[1024 + t] + ss[1536 + t];
  float p1 = ss[256 + t] + ss[768 + t] + ss[1280 + t] + ss[1792 + t];
  part[(size_t)blockIdx.x * 512 + t] = p0;
  part[(size_t)blockIdx.x * 512 + 256 + t] = p1;
}

// reduce AGG_BLOCKS x 512 partials -> stats[512]; 16 blocks, tiny atomic fan-in
__global__ void k_bn_reduce(const float* __restrict__ part, float* __restrict__ stats) {
  int i = threadIdx.x;            // 0..255
  int base = blockIdx.x * (AGG_BLOCKS / 16);
  float s0 = 0.f, s1 = 0.f;
  for (int b = 0; b < AGG_BLOCKS / 16; b++) {
    s0 += part[(size_t)(base + b) * 512 + i];
    s1 += part[(size_t)(base + b) * 512 + 256 + i];
  }
  atomicAdd(&stats[i], s0);
  atomicAdd(&stats[256 + i], s1);
}

// BN + ReLU (+ optional fp16 residual add): fp16 in -> bf16 out
__global__ void k_bn_relu_cvt(const _Float16* __restrict__ X, const float* __restrict__ stats,
                              const float* __restrict__ g, const float* __restrict__ b,
                              const _Float16* __restrict__ resid, ushort* __restrict__ Xb) {
  size_t i = ((size_t)blockIdx.x * 256 + threadIdx.x) * 4;
  int c = (int)(i & 255);
  const float invN = 1.f / (float)N_NODES;
  h4v x4 = *(const h4v*)&X[i];
  float4 s4 = *(const float4*)&stats[c];
  float4 q4 = *(const float4*)&stats[256 + c];
  float4 g4 = *(const float4*)&g[c];
  float4 b4 = *(const float4*)&b[c];
  float m0 = s4.x * invN, m1 = s4.y * invN, m2 = s4.z * invN, m3 = s4.w * invN;
  float v0 = ((float)x4[0] - m0) * rsqrtf(q4.x * invN - m0 * m0 + 1e-5f) * g4.x + b4.x;
  float v1 = ((float)x4[1] - m1) * rsqrtf(q4.y * invN - m1 * m1 + 1e-5f) * g4.y + b4.y;
  float v2 = ((float)x4[2] - m2) * rsqrtf(q4.z * invN - m2 * m2 + 1e-5f) * g4.z + b4.z;
  float v3 = ((float)x4[3] - m3) * rsqrtf(q4.w * invN - m3 * m3 + 1e-5f) * g4.w + b4.w;
  v0 = v0 > 0.f ? v0 : 0.f; v1 = v1 > 0.f ? v1 : 0.f;
  v2 = v2 > 0.f ? v2 : 0.f; v3 = v3 > 0.f ? v3 : 0.f;
  if (resid) {
    h4v r4 = *(const h4v*)&resid[i];
    v0 += (float)r4[0]; v1 += (float)r4[1]; v2 += (float)r4[2]; v3 += (float)r4[3];
  }
  ushort4 ob;
  ob.x = f2bf(v0); ob.y = f2bf(v1); ob.z = f2bf(v2); ob.w = f2bf(v3);
  *(ushort4*)&Xb[i] = ob;
}

// ---------------------------------------------------------------- decode epilogue (one wave / node)
__launch_bounds__(256)
__global__ void k_dec(const _Float16* __restrict__ Hd, const float* __restrict__ eps,
                      const float* __restrict__ mub, const float* __restrict__ lvb,
                      const float* __restrict__ auxb,
                      const float* __restrict__ decW, const float* __restrict__ decb,
                      float* __restrict__ out) {
  __shared__ float wsd[2048];   // decW [32][64]
  __shared__ float shz[4][32];
  int t = threadIdx.x;
  for (int i = t; i < 2048; i += 256) wsd[i] = decW[i];
  int w = t >> 6, lane = t & 63;
  int n = blockIdx.x * 4 + w;
  const _Float16* hd = &Hd[(size_t)n * 128];
  if (lane < 32) {
    float mu = (float)hd[lane] + mub[lane];
    float lv = (float)hd[32 + lane] + lvb[lane];
    out[(size_t)N_NODES * 64 + (size_t)n * 32 + lane] = mu;
    out[(size_t)N_NODES * 96 + (size_t)n * 32 + lane] = lv;
    shz[w][lane] = mu + eps[(size_t)n * 32 + lane] * __expf(0.5f * lv);
  } else if (lane < 62) {
    int j = lane - 32;
    out[(size_t)N_NODES * 128 + (size_t)n * 30 + j] = (float)hd[64 + j] + auxb[j];
  }
  __syncthreads();
  float o = decb[lane];
#pragma unroll 8
  for (int k = 0; k < 32; k++) o += shz[w][k] * wsd[k * 64 + lane];
  out[(size_t)n * 64 + lane] = o;
}

// ---------------------------------------------------------------- launch
extern "C" void kernel_launch(void* const* d_in, const int* in_sizes, int n_in,
                              void* d_out, int out_size, void* d_ws, size_t ws_size,
                              hipStream_t stream) {
  (void)in_sizes; (void)n_in; (void)out_size; (void)ws_size;
  const float* x    = (const float*)d_in[0];
  const float* eps  = (const float*)d_in[1];
  const int*   ei   = (const int*)d_in[2];
  const float* gW[3]    = {(const float*)d_in[3],  (const float*)d_in[9],  (const float*)d_in[15]};
  const float* gasrc[3] = {(const float*)d_in[4],  (const float*)d_in[10], (const float*)d_in[16]};
  const float* gadst[3] = {(const float*)d_in[5],  (const float*)d_in[11], (const float*)d_in[17]};
  const float* gbias[3] = {(const float*)d_in[6],  (const float*)d_in[12], (const float*)d_in[18]};
  const float* bng[3]   = {(const float*)d_in[7],  (const float*)d_in[13], (const float*)d_in[19]};
  const float* bnb[3]   = {(const float*)d_in[8],  (const float*)d_in[14], (const float*)d_in[20]};
  const float* resW = (const float*)d_in[21];
  const float* resb = (const float*)d_in[22];
  const float* muW  = (const float*)d_in[23];
  const float* mub  = (const float*)d_in[24];
  const float* lvW  = (const float*)d_in[25];
  const float* lvb  = (const float*)d_in[26];
  const float* decW = (const float*)d_in[27];
  const float* decb = (const float*)d_in[28];
  const float* auxW = (const float*)d_in[29];
  const float* auxb = (const float*)d_in[30];
  float* out = (float*)d_out;

  char* ws = (char*)d_ws;
  size_t off = 0;
  auto alloc = [&](size_t bytes) -> void* {
    void* p = ws + off;
    off += (bytes + 255) & ~(size_t)255;
    return p;
  };
  _Float16* X0  = (_Float16*)alloc((size_t)N_NODES * HC * 2);  // GEMM out / att input (fp16)
  _Float16* X1  = (_Float16*)alloc((size_t)N_NODES * HC * 2);  // agg output (fp16)
  _Float16* Rr  = (_Float16*)alloc((size_t)N_NODES * HC * 2);  // residual (fp16)
  _Float16* Hd  = (_Float16*)alloc((size_t)N_NODES * 128 * 2); // head GEMM out (fp16)
  ushort* Xb    = (ushort*)alloc((size_t)N_NODES * HC * 2);    // bf16 activations
  float*  as_   = (float*)alloc((size_t)N_NODES * NH * 4);
  float*  ad_   = (float*)alloc((size_t)N_NODES * NH * 4);
  float*  stats = (float*)alloc(512 * 4);
  float*  part  = (float*)alloc((size_t)AGG_BLOCKS * 512 * 4); // 4 MB BN partials
  int* cnt      = (int*)alloc((size_t)N_NODES * 4);
  int* rowptr   = (int*)alloc((size_t)(N_NODES + 1) * 4);
  int* fillptr  = (int*)alloc((size_t)N_NODES * 4);
  int* srcs     = (int*)alloc((size_t)(N_NODES + N_EDGES) * 4);
  int* bsum     = (int*)alloc(256 * 4);
  ushort* Wt1   = (ushort*)alloc(256 * 128 * 2);
  ushort* Wt2   = (ushort*)alloc(256 * 256 * 2);
  ushort* Wt3   = (ushort*)alloc(256 * 256 * 2);
  ushort* WtR   = (ushort*)alloc(256 * 128 * 2);
  ushort* Wth   = (ushort*)alloc(128 * 256 * 2);

  const int NB = (N_NODES + 255) / 256;
  // CSR build
  k_init_cnt<<<NB, 256, 0, stream>>>(cnt);
  k_count<<<(N_EDGES + 255) / 256, 256, 0, stream>>>(ei + N_EDGES, cnt);
  k_scan_bsum<<<NB, 256, 0, stream>>>(cnt, bsum);
  k_scan_offsets<<<1, 256, 0, stream>>>(bsum, NB);
  k_scan_write<<<NB, 256, 0, stream>>>(cnt, bsum, rowptr, fillptr);
  k_fill<<<(N_NODES + N_EDGES + 255) / 256, 256, 0, stream>>>(ei, ei + N_EDGES, fillptr, srcs);

  // weight prep
  k_cvt_wt<<<dim3(4, 8), 256, 0, stream>>>(gW[0], Wt1, 128, 256);
  k_cvt_wt<<<dim3(8, 8), 256, 0, stream>>>(gW[1], Wt2, 256, 256);
  k_cvt_wt<<<dim3(8, 8), 256, 0, stream>>>(gW[2], Wt3, 256, 256);
  k_cvt_wt<<<dim3(4, 8), 256, 0, stream>>>(resW, WtR, 128, 256);
  k_pack_head<<<128, 256, 0, stream>>>(muW, lvW, auxW, Wth);
  // x -> bf16
  k_cvt_x<<<(N_NODES * 128) / 1024, 256, 0, stream>>>(x, Xb);

  const int GM = (N_NODES + 127) / 128;  // 391
  // residual = x @ res_W + res_b (fp16 out)
  k_gemm_bf16<_Float16><<<dim3(GM, 2), 256, 0, stream>>>(Xb, WtR, resb, Rr, N_NODES, 128, 256);

  const ushort* Wts[3] = {Wt1, Wt2, Wt3};
  int K = 128;
  for (int L = 0; L < 3; L++) {
    k_gemm_bf16<_Float16><<<dim3(GM, 2), 256, 0, stream>>>(Xb, Wts[L], nullptr, X0, N_NODES, K, 256);
    k_att<<<N_NODES / 4, 256, 0, stream>>>(X0, gasrc[L], gadst[L], as_, ad_);
    k_agg<<<AGG_BLOCKS, 256, 0, stream>>>(rowptr, srcs, as_, ad_, X0, gbias[L], X1, part, stats);
    k_bn_reduce<<<16, 256, 0, stream>>>(part, stats);
    k_bn_relu_cvt<<<(N_NODES * HC) / 1024, 256, 0, stream>>>(
        X1, stats, bng[L], bnb[L], (L == 2) ? Rr : nullptr, Xb);
    K = 256;
  }
  // heads: Hd = h @ [muW|lvW|auxW|0] (fp16 out)
  k_gemm_bf16<_Float16><<<dim3(GM, 1), 256, 0, stream>>>(Xb, Wth, nullptr, Hd, N_NODES, 256, 128);
  k_dec<<<N_NODES / 4, 256, 0, stream>>>(Hd, eps, mub, lvb, auxb, decW, decb, out);
}